// Round 2
// baseline (8493.841 us; speedup 1.0000x reference)
//
#include <hip/hip_runtime.h>
#include <hip/hip_bf16.h>

#define BATCH 64
#define HID 512
#define EMB 256
#define VOCAB 32000
#define G4 (4*HID)   // 2048

// ---------------- zero init ----------------
__global__ __launch_bounds__(256) void zero_kernel(float* p, int n){
    int i = blockIdx.x*256 + threadIdx.x;
    if (i < n) p[i] = 0.f;
}

// ---------------- embedding gather ----------------
// out[t,b,:] = emb[tok[t*BATCH+b], :], one float4 per thread
__global__ __launch_bounds__(256) void embed_kernel(const int* __restrict__ tok,
                                                    const float* __restrict__ emb,
                                                    float* __restrict__ out, int T){
    int i = blockIdx.x*256 + threadIdx.x;
    int n = T*BATCH*(EMB/4);
    if (i >= n) return;
    int e4 = i % (EMB/4);
    int tb = i / (EMB/4);
    int id = tok[tb];
    reinterpret_cast<float4*>(out)[(size_t)tb*(EMB/4) + e4] =
        reinterpret_cast<const float4*>(emb + (size_t)id*EMB)[e4];
}

// ---------------- generic fp32 GEMM:  C[n,m] = A[n,:K] . B[m,:K] + bias[m] ----------------
// N,M multiples of 64; K multiple of 16. fp32 output.
__global__ __launch_bounds__(256) void gemm_nt(const float* __restrict__ A,
                                               const float* __restrict__ B,
                                               const float* __restrict__ bias,
                                               float* __restrict__ C,
                                               int N, int M, int K){
    __shared__ float As[16][65];
    __shared__ float Bs[16][65];
    int m0 = blockIdx.x*64, n0 = blockIdx.y*64;
    int tid = threadIdx.x;
    int tx = tid & 15, ty = tid >> 4;
    float acc[4][4] = {};
    for (int k0 = 0; k0 < K; k0 += 16){
        for (int i = tid; i < 64*16; i += 256){
            int r = i >> 4, k = i & 15;
            As[k][r] = A[(size_t)(n0+r)*K + k0 + k];
            Bs[k][r] = B[(size_t)(m0+r)*K + k0 + k];
        }
        __syncthreads();
        #pragma unroll
        for (int k = 0; k < 16; k++){
            float a[4], b[4];
            #pragma unroll
            for (int i = 0; i < 4; i++) a[i] = As[k][ty*4+i];
            #pragma unroll
            for (int j = 0; j < 4; j++) b[j] = Bs[k][tx*4+j];
            #pragma unroll
            for (int i = 0; i < 4; i++)
                #pragma unroll
                for (int j = 0; j < 4; j++)
                    acc[i][j] += a[i]*b[j];
        }
        __syncthreads();
    }
    #pragma unroll
    for (int i = 0; i < 4; i++){
        int n = n0 + ty*4 + i;
        #pragma unroll
        for (int j = 0; j < 4; j++){
            int m = m0 + tx*4 + j;
            C[(size_t)n*M + m] = acc[i][j] + bias[m];
        }
    }
}

// ---------------- one LSTM time step (recurrent matvec + gates fused) ----------------
// xp: [BATCH, 4H] precomputed x@Wih^T + b for this t; Whh: [4H, HID] row-major
// Each thread owns one (b, hid) pair and computes all 4 gate dots -> c,h update.
// Block: 256 thr = 32 hid x 8 b. Grid: (HID/32=16, BATCH/8=8).
__global__ __launch_bounds__(256) void lstm_step(const float* __restrict__ xp,
                                                 const float* __restrict__ Whh,
                                                 const float* __restrict__ hprev,
                                                 float* __restrict__ cbuf,
                                                 float* __restrict__ hout){
    __shared__ float hs[8][HID];      // 16 KB
    __shared__ float ws[128][65];     // 33.3 KB, padded vs bank conflicts
    const int hid0 = blockIdx.x*32;
    const int b0   = blockIdx.y*8;
    const int tid  = threadIdx.x;
    const int hl = tid & 31, bl = tid >> 5;

    // stage the 8 h rows once
    for (int i = tid; i < 8*HID; i += 256)
        hs[i>>9][i&511] = hprev[(size_t)(b0 + (i>>9))*HID + (i&511)];

    float acc[4] = {0.f,0.f,0.f,0.f};
    for (int k0 = 0; k0 < HID; k0 += 64){
        __syncthreads();              // covers hs on first iter, ws reuse after
        for (int i = tid; i < 128*64; i += 256){
            int r = i >> 6, k = i & 63;
            int gr = (r >> 5)*HID + hid0 + (r & 31);   // gate*512 + hid
            ws[r][k] = Whh[(size_t)gr*HID + k0 + k];
        }
        __syncthreads();
        #pragma unroll 4
        for (int k = 0; k < 64; k++){
            float hv = hs[bl][k0+k];
            #pragma unroll
            for (int g = 0; g < 4; g++)
                acc[g] += hv * ws[g*32 + hl][k];
        }
    }

    const int b = b0 + bl, hid = hid0 + hl;
    const float* xpr = xp + (size_t)b*G4;
    float gi = acc[0] + xpr[hid];
    float gf = acc[1] + xpr[HID   + hid];
    float gg = acc[2] + xpr[2*HID + hid];
    float go = acc[3] + xpr[3*HID + hid];
    float si = 1.f/(1.f + expf(-gi));
    float sf = 1.f/(1.f + expf(-gf));
    float so = 1.f/(1.f + expf(-go));
    float tg = tanhf(gg);
    size_t idx = (size_t)b*HID + hid;
    float c = sf*cbuf[idx] + si*tg;
    cbuf[idx] = c;
    hout[idx] = so * tanhf(c);
}

extern "C" void kernel_launch(void* const* d_in, const int* in_sizes, int n_in,
                              void* d_out, int out_size, void* d_ws, size_t ws_size,
                              hipStream_t stream) {
    const int*   src      = (const int*)  d_in[0];
    const int*   trg      = (const int*)  d_in[1];
    const float* enc_emb  = (const float*)d_in[2];
    const float* enc_Wih0 = (const float*)d_in[3];
    const float* enc_Whh0 = (const float*)d_in[4];
    const float* enc_b0   = (const float*)d_in[5];
    const float* enc_Wih1 = (const float*)d_in[6];
    const float* enc_Whh1 = (const float*)d_in[7];
    const float* enc_b1   = (const float*)d_in[8];
    const float* dec_emb  = (const float*)d_in[9];
    const float* dec_Wih0 = (const float*)d_in[10];
    const float* dec_Whh0 = (const float*)d_in[11];
    const float* dec_b0   = (const float*)d_in[12];
    const float* dec_Wih1 = (const float*)d_in[13];
    const float* dec_Whh1 = (const float*)d_in[14];
    const float* dec_b1   = (const float*)d_in[15];
    const float* out_W    = (const float*)d_in[16];
    const float* out_b    = (const float*)d_in[17];

    // Big transient scratch lives in d_out (fp32, 100.35M elements = 401 MB).
    // Everything placed here is dead before the final projection overwrites d_out.
    float* ob = (float*)d_out;
    float* Xp   = ob;                         // [3200,2048]  -> 6,553,600
    float* xe   = ob + (size_t)6553600;       // [3200,256]   -> +819,200
    float* xd   = ob + (size_t)7372800;       // [3136,256]   -> +802,816
    float* eys0 = ob + (size_t)8175616;       // [50*64,512]  -> +1,638,400
    float* eys1 = ob + (size_t)9814016;       // [50*64,512]  -> +1,638,400
    float* dys0 = ob + (size_t)11452416;      // [49*64,512]  -> +1,605,632 (end 13,058,048 < 100,352,000)

    // d_ws holds only what must survive into the final GEMM (6.8 MB).
    float* ws = (float*)d_ws;
    float* dys1 = ws;                         // [49*64,512] = 1,605,632
    float* c0   = ws + (size_t)1605632;       // c0,c1,hz contiguous
    float* c1   = ws + (size_t)1638400;
    float* hz   = ws + (size_t)1671168;

    // zero c0, c1, hz (contiguous 3*BATCH*HID)
    {
        int n = 3*BATCH*HID;
        zero_kernel<<<(n+255)/256, 256, 0, stream>>>(c0, n);
    }

    // embeddings
    embed_kernel<<<(50*BATCH*(EMB/4)+255)/256, 256, 0, stream>>>(src, enc_emb, xe, 50);
    embed_kernel<<<(49*BATCH*(EMB/4)+255)/256, 256, 0, stream>>>(trg, dec_emb, xd, 49);

    dim3 rgrid(16, 8);

    // ---- encoder layer 0 ----
    gemm_nt<<<dim3(G4/64, 3200/64), 256, 0, stream>>>(xe, enc_Wih0, enc_b0, Xp, 3200, G4, EMB);
    for (int t = 0; t < 50; t++){
        const float* hp = (t == 0) ? hz : (eys0 + (size_t)(t-1)*BATCH*HID);
        lstm_step<<<rgrid, 256, 0, stream>>>(Xp + (size_t)t*BATCH*G4, enc_Whh0, hp, c0,
                                             eys0 + (size_t)t*BATCH*HID);
    }
    // ---- encoder layer 1 ----
    gemm_nt<<<dim3(G4/64, 3200/64), 256, 0, stream>>>(eys0, enc_Whh1 ? enc_Wih1 : enc_Wih1, enc_b1, Xp, 3200, G4, HID);
    for (int t = 0; t < 50; t++){
        const float* hp = (t == 0) ? hz : (eys1 + (size_t)(t-1)*BATCH*HID);
        lstm_step<<<rgrid, 256, 0, stream>>>(Xp + (size_t)t*BATCH*G4, enc_Whh1, hp, c1,
                                             eys1 + (size_t)t*BATCH*HID);
    }
    // ---- decoder layer 0 (states continue from encoder layer 0) ----
    gemm_nt<<<dim3(G4/64, 3136/64), 256, 0, stream>>>(xd, dec_Wih0, dec_b0, Xp, 3136, G4, EMB);
    for (int t = 0; t < 49; t++){
        const float* hp = (t == 0) ? (eys0 + (size_t)49*BATCH*HID)
                                   : (dys0 + (size_t)(t-1)*BATCH*HID);
        lstm_step<<<rgrid, 256, 0, stream>>>(Xp + (size_t)t*BATCH*G4, dec_Whh0, hp, c0,
                                             dys0 + (size_t)t*BATCH*HID);
    }
    // ---- decoder layer 1 (states continue from encoder layer 1) ----
    gemm_nt<<<dim3(G4/64, 3136/64), 256, 0, stream>>>(dys0, dec_Wih1, dec_b1, Xp, 3136, G4, HID);
    for (int t = 0; t < 49; t++){
        const float* hp = (t == 0) ? (eys1 + (size_t)49*BATCH*HID)
                                   : (dys1 + (size_t)(t-1)*BATCH*HID);
        lstm_step<<<rgrid, 256, 0, stream>>>(Xp + (size_t)t*BATCH*G4, dec_Whh1, hp, c1,
                                             dys1 + (size_t)t*BATCH*HID);
    }

    // ---- final projection -> fp32 d_out [3136, 32000] ----
    // Reads only dys1 (in d_ws) + weights; overwrites all of d_out.
    gemm_nt<<<dim3(VOCAB/64, 3136/64), 256, 0, stream>>>(dys1, out_W, out_b, (float*)d_out,
                                                         3136, VOCAB, HID);
}